// Round 18
// baseline (114.406 us; speedup 1.0000x reference)
//
#include <hip/hip_runtime.h>
#include <hip/hip_bf16.h>
#include <math.h>

#define Nn    512
#define CS    384
#define CZ    128
#define CH    16
#define Hh    12
#define PQ    4
#define PV    8
#define NCOL  1152   // 192*3 + 144*2 + 288
#define FIN   2112

#define W_C   0.23570226039551584f   // sqrt(2/(9*4))
#define W_L   0.5773502691896258f    // sqrt(1/3)

typedef unsigned short ushort_t;
typedef unsigned int uint_t;
typedef __attribute__((ext_vector_type(8))) short bf16x8;
typedef __attribute__((ext_vector_type(4))) float f32x4;

// ---------------- workspace layout (float offsets) ----------------
#define OFF_P      0u
#define OFF_MQ     589824u
#define OFF_MK     595968u
#define OFF_VT     602112u      // v16T  [192][512] bf16
#define OFF_VPT    651264u      // vpgT  [288][512] bf16
#define OFF_S16    1830912u     // s bf16 [512][384]
#define OFF_WCT    1929216u     // WcatT bf16 [1152][384]
#define OFF_WFT    2150400u     // WfT bf16 [384][2112]
#define OFF_F16    2555904u     // feat bf16 [512][2112] (ends 3096576)
#define OFF_VFRAG  5328896u     // vfrag bf16 [30][16][64][8]
#define OFF_EXT    5451776u     // ext f32 [12][512][512] (ends 8597504)
#define OFF_EKB    21755904u    // ekb bf16 [6144][32]
#define OFF_EQB    21854208u    // eqb bf16 [6144][32]
#define OFF_WBF    21952512u

__device__ inline ushort_t f2bf(float f) {
  __hip_bfloat16 h = __float2bfloat16(f);
  return *reinterpret_cast<ushort_t*>(&h);
}
__device__ inline float bf2f(ushort_t u) {
  unsigned int x = ((unsigned int)u) << 16;
  return __uint_as_float(x);
}

// ====== K0: fused converters: s16 | WcatT | WfT | wbf (one launch) ==========
__global__ __launch_bounds__(384) void k_conv(
    const float* __restrict__ s, const float* __restrict__ Wq,
    const float* __restrict__ Wk, const float* __restrict__ Wv,
    const float* __restrict__ Wqp, const float* __restrict__ Wkp,
    const float* __restrict__ Wvp, const float* __restrict__ Wf,
    const float* __restrict__ Wb,
    ushort_t* __restrict__ s16, ushort_t* __restrict__ WcatT,
    ushort_t* __restrict__ WfT, ushort_t* __restrict__ wbf) {
  int b = blockIdx.x;
  if (b < 512) {
    int idx = b * 384 + threadIdx.x;
    s16[idx] = f2bf(s[idx]);
  } else if (b < 1664) {
    int col = b - 512, k = threadIdx.x;
    float v;
    if      (col < 192)  v = Wq [k * 192 + col];
    else if (col < 384)  v = Wk [k * 192 + col - 192];
    else if (col < 576)  v = Wv [k * 192 + col - 384];
    else if (col < 720)  v = Wqp[k * 144 + col - 576];
    else if (col < 864)  v = Wkp[k * 144 + col - 720];
    else                 v = Wvp[k * 288 + col - 864];
    WcatT[(size_t)col * CS + k] = f2bf(v);
  } else if (b < 2048) {
    int o = b - 1664;
    for (int f = threadIdx.x; f < FIN; f += 384)
      WfT[(size_t)o * FIN + f] = f2bf(Wf[(size_t)f * CS + o]);
  } else {
    int t = threadIdx.x;
    if (t < 256) {
      int kk = t >> 6, l = t & 63;
      int h = l & 15, lk = l >> 4;
#pragma unroll
      for (int e = 0; e < 8; ++e) {
        int c = kk * 32 + lk * 8 + e;
        wbf[t * 8 + e] = (h < Hh) ? f2bf(Wb[c * Hh + h]) : (ushort_t)0;
      }
    }
  }
}

// ============ K1: proj via MFMA (dual-acc ILP): P = s16 @ WcatT^T ===========
__global__ __launch_bounds__(64) void k_projm(
    const ushort_t* __restrict__ s16, const ushort_t* __restrict__ WcatT,
    float* __restrict__ P) {
  int colt = blockIdx.x;
  int i0 = blockIdx.y * 16;
  int l = threadIdx.x;
  int cl = l & 15, lk = l >> 4;
  f32x4 accA = {0.f, 0.f, 0.f, 0.f}, accB = {0.f, 0.f, 0.f, 0.f};
  const ushort_t* arow = s16 + (size_t)(i0 + cl) * CS;
  const ushort_t* brow = WcatT + (size_t)(colt * 16 + cl) * CS;
#pragma unroll
  for (int kk = 0; kk < 12; kk += 2) {
    bf16x8 a0 = *(const bf16x8*)(arow + kk * 32 + lk * 8);
    bf16x8 b0 = *(const bf16x8*)(brow + kk * 32 + lk * 8);
    accA = __builtin_amdgcn_mfma_f32_16x16x32_bf16(a0, b0, accA, 0, 0, 0);
    bf16x8 a1 = *(const bf16x8*)(arow + (kk + 1) * 32 + lk * 8);
    bf16x8 b1 = *(const bf16x8*)(brow + (kk + 1) * 32 + lk * 8);
    accB = __builtin_amdgcn_mfma_f32_16x16x32_bf16(a1, b1, accB, 0, 0, 0);
  }
#pragma unroll
  for (int r = 0; r < 4; ++r)
    P[(size_t)(i0 + lk * 4 + r) * NCOL + colt * 16 + cl] = accA[r] + accB[r];
}

// ===== K1b: rigid transforms -> eqb/ekb bf16, mq/mk, vT, vpT ================
__global__ __launch_bounds__(64) void k_prep(
    const float* __restrict__ P, const float* __restrict__ rot,
    const float* __restrict__ trans, const float* __restrict__ gamma,
    ushort_t* __restrict__ eqb, ushort_t* __restrict__ ekb,
    float* __restrict__ mq, float* __restrict__ mk,
    ushort_t* __restrict__ vT, ushort_t* __restrict__ vpT) {
  int gid = blockIdx.x * 64 + threadIdx.x;        // < 6144
  int i = gid / Hh, h = gid % Hh;
  const float* Pi = P + (size_t)i * NCOL;
  float R[9], T[3];
#pragma unroll
  for (int m = 0; m < 9; ++m) R[m] = rot[i * 9 + m];
#pragma unroll
  for (int m = 0; m < 3; ++m) T[m] = trans[i * 3 + m];
  float cg = W_C * gamma[h];

  ushort_t* eq = eqb + (size_t)gid * 32;
  ushort_t* ek = ekb + (size_t)gid * 32;
#pragma unroll
  for (int d = 0; d < CH; ++d) eq[d] = f2bf(Pi[h * CH + d] * 0.25f);
#pragma unroll
  for (int d = 0; d < CH; ++d) ek[d] = f2bf(Pi[192 + h * CH + d]);
  float sq = 0.f, sk = 0.f;
#pragma unroll
  for (int p = 0; p < PQ; ++p) {
    float x = Pi[576 + h * 12 + p * 3 + 0];
    float y = Pi[576 + h * 12 + p * 3 + 1];
    float zc = Pi[576 + h * 12 + p * 3 + 2];
    float gx = R[0] * x + R[1] * y + R[2] * zc + T[0];
    float gy = R[3] * x + R[4] * y + R[5] * zc + T[1];
    float gz = R[6] * x + R[7] * y + R[8] * zc + T[2];
    eq[16 + p * 3 + 0] = f2bf(cg * gx);
    eq[16 + p * 3 + 1] = f2bf(cg * gy);
    eq[16 + p * 3 + 2] = f2bf(cg * gz);
    sq += gx * gx + gy * gy + gz * gz;
  }
#pragma unroll
  for (int p = 0; p < PQ; ++p) {
    float x = Pi[720 + h * 12 + p * 3 + 0];
    float y = Pi[720 + h * 12 + p * 3 + 1];
    float zc = Pi[720 + h * 12 + p * 3 + 2];
    float gx = R[0] * x + R[1] * y + R[2] * zc + T[0];
    float gy = R[3] * x + R[4] * y + R[5] * zc + T[1];
    float gz = R[6] * x + R[7] * y + R[8] * zc + T[2];
    ek[16 + p * 3 + 0] = f2bf(gx);
    ek[16 + p * 3 + 1] = f2bf(gy);
    ek[16 + p * 3 + 2] = f2bf(gz);
    sk += gx * gx + gy * gy + gz * gz;
  }
#pragma unroll
  for (int d = 28; d < 32; ++d) { eq[d] = 0; ek[d] = 0; }
  mq[gid] = -0.5f * cg * sq;
  mk[gid] = -0.5f * cg * sk;

#pragma unroll
  for (int d = 0; d < CH; ++d)
    vT[(size_t)(h * CH + d) * Nn + i] = f2bf(Pi[384 + h * CH + d]);
#pragma unroll
  for (int p = 0; p < PV; ++p) {
    float x = Pi[864 + h * 24 + p * 3 + 0];
    float y = Pi[864 + h * 24 + p * 3 + 1];
    float zc = Pi[864 + h * 24 + p * 3 + 2];
    vpT[(size_t)(h * 24 + p * 3 + 0) * Nn + i] = f2bf(R[0] * x + R[1] * y + R[2] * zc + T[0]);
    vpT[(size_t)(h * 24 + p * 3 + 1) * Nn + i] = f2bf(R[3] * x + R[4] * y + R[5] * zc + T[1]);
    vpT[(size_t)(h * 24 + p * 3 + 2) * Nn + i] = f2bf(R[6] * x + R[7] * y + R[8] * zc + T[2]);
  }
}

// ===== K1d: merged aux: ext (blocks 0..1023) | vfrag (blocks 1024..1063) ====
__global__ __launch_bounds__(768) void k_aux(
    const ushort_t* __restrict__ eqb, const ushort_t* __restrict__ ekb,
    const float* __restrict__ mk, float* __restrict__ ext,
    const ushort_t* __restrict__ vT, const ushort_t* __restrict__ vpT,
    ushort_t* __restrict__ vfrag) {
  int b = blockIdx.x, tid = threadIdx.x;
  if (b < 1024) {                                  // ext: 12 head-GEMMs
    int it = b >> 5, jt = b & 31;
    int l = tid & 63, h = tid >> 6;                // wave = head 0..11
    int cl = l & 15, lk = l >> 4;
    bf16x8 a = *(const bf16x8*)(eqb + ((size_t)(it * 16 + cl) * Hh + h) * 32 + lk * 8);
    bf16x8 bb = *(const bf16x8*)(ekb + ((size_t)(jt * 16 + cl) * Hh + h) * 32 + lk * 8);
    f32x4 dl = {0.f, 0.f, 0.f, 0.f};
    dl = __builtin_amdgcn_mfma_f32_16x16x32_bf16(a, bb, dl, 0, 0, 0);
    float mkv = mk[(jt * 16 + cl) * Hh + h];
    float* erow = ext + ((size_t)h * Nn + it * 16 + lk * 4) * Nn + jt * 16 + cl;
#pragma unroll
    for (int r = 0; r < 4; ++r) erow[(size_t)r * Nn] = dl[r] + mkv;
  } else {                                         // vfrag: 30720 items
    int flat = (b - 1024) * 768 + tid;
    if (flat < 30720) {
      int tt = flat >> 10;
      int r = flat & 1023;
      int jb = r >> 6, l = r & 63;
      int cl = l & 15, lk = l >> 4;
      const ushort_t* src = (tt < 12)
          ? vT  + (size_t)(tt * 16 + cl) * Nn
          : vpT + (size_t)((tt - 12) * 16 + cl) * Nn;
      bf16x8 v = *(const bf16x8*)(src + jb * 32 + lk * 8);
      *(bf16x8*)(vfrag + (((size_t)tt * 16 + jb) * 64 + l) * 8) = v;
    }
  }
}

// ==== K2: fused flash, ONE block per i, two j-halves in-loop, writes feat16 ==
__global__ __launch_bounds__(512, 4) void k_fused10(
    const float* __restrict__ z, const ushort_t* __restrict__ wbf,
    const float* __restrict__ ext, const ushort_t* __restrict__ vfrag,
    const float* __restrict__ rot, const float* __restrict__ trans,
    ushort_t* __restrict__ feat16) {
  __shared__ float smemf[20256];                   // 81024 B -> 2 blocks/CU
  char*     ztc  = (char*)smemf;                   // [256][128] bf16 swz (64KB)
  char*     pB   = (char*)smemf + 65536;           // [16][256] u16 swz (8KB)
  ushort_t* extb = (ushort_t*)((char*)smemf + 73728); // [256][12] bf16 (6KB)
  float*    mb   = smemf + 19968;                  // [8][16]
  float*    lb   = smemf + 20096;                  // [8][16]
  float*    Mv   = smemf + 20224;                  // [16] per-iter target max
  float*    Mrun = smemf + 20240;                  // [16] (union half: also Lv)
  // Lrun lives in the same 16 threads' registers (tid<16 only)

  int i = blockIdx.x, tid = threadIdx.x;
  int l = tid & 63, w = tid >> 6;                  // 8 waves
  int cl = l & 15, lk = l >> 4;
  ushort_t* Fi = feat16 + (size_t)i * FIN;
  int swz = (cl & 7) << 4;

  float L_run = 0.f;                               // valid in tid<16 only
  if (tid < 16) Mrun[tid] = -1e30f;

  bf16x8 wbreg[4];
#pragma unroll
  for (int kk = 0; kk < 4; ++kk)
    wbreg[kk] = *(const bf16x8*)&wbf[(kk * 64 + l) * 8];

  f32x4 acc[5];
#pragma unroll
  for (int n = 0; n < 5; ++n) acc[n] = (f32x4){0.f, 0.f, 0.f, 0.f};

  for (int half = 0; half < 2; ++half) {
    int j0b = half * 256;

    // ---- per-wave staging: OWN 32 z-rows (16 f4/lane) + OWN ext slice ----
    const float4* zg4 = (const float4*)(z + ((size_t)i * Nn + j0b) * CZ);
    float4 xv0 = zg4[w * 1024 + 0 * 64 + l],  xv1 = zg4[w * 1024 + 1 * 64 + l];
    float4 xv2 = zg4[w * 1024 + 2 * 64 + l],  xv3 = zg4[w * 1024 + 3 * 64 + l];
    float4 xv4 = zg4[w * 1024 + 4 * 64 + l],  xv5 = zg4[w * 1024 + 5 * 64 + l];
    float4 xv6 = zg4[w * 1024 + 6 * 64 + l],  xv7 = zg4[w * 1024 + 7 * 64 + l];
    float4 xv8 = zg4[w * 1024 + 8 * 64 + l],  xv9 = zg4[w * 1024 + 9 * 64 + l];
    float4 xv10 = zg4[w * 1024 + 10 * 64 + l], xv11 = zg4[w * 1024 + 11 * 64 + l];
    float4 xv12 = zg4[w * 1024 + 12 * 64 + l], xv13 = zg4[w * 1024 + 13 * 64 + l];
    float4 xv14 = zg4[w * 1024 + 14 * 64 + l], xv15 = zg4[w * 1024 + 15 * 64 + l];
    float ev[6];
#pragma unroll
    for (int q = 0; q < 6; ++q) {
      int flat = q * 64 + l;                       // 0..383 = 12h x 32jl
      int eh = flat >> 5, ejl = flat & 31;
      ev[q] = ext[((size_t)eh * Nn + i) * Nn + j0b + w * 32 + ejl];
    }

#define STORE_ZT(it_, xv_) { \
    int idxl = (it_) * 64 + l; \
    int row = w * 32 + (idxl >> 5), c4 = idxl & 31; \
    uint2 pk; \
    pk.x = (uint_t)f2bf(xv_.x) | ((uint_t)f2bf(xv_.y) << 16); \
    pk.y = (uint_t)f2bf(xv_.z) | ((uint_t)f2bf(xv_.w) << 16); \
    *(uint2*)&ztc[row * 256 + ((c4 * 8) ^ ((row & 7) << 4))] = pk; }
    STORE_ZT(0, xv0)   STORE_ZT(1, xv1)   STORE_ZT(2, xv2)   STORE_ZT(3, xv3)
    STORE_ZT(4, xv4)   STORE_ZT(5, xv5)   STORE_ZT(6, xv6)   STORE_ZT(7, xv7)
    STORE_ZT(8, xv8)   STORE_ZT(9, xv9)   STORE_ZT(10, xv10) STORE_ZT(11, xv11)
    STORE_ZT(12, xv12) STORE_ZT(13, xv13) STORE_ZT(14, xv14) STORE_ZT(15, xv15)
#undef STORE_ZT
#pragma unroll
    for (int q = 0; q < 6; ++q) {
      int flat = q * 64 + l;
      extb[(w * 32 + (flat & 31)) * 12 + (flat >> 5)] = f2bf(ev[q]);
    }

    // ---- Phase 1 (NO barrier: reads only own-wave rows) ----
    float v[2][4];
#pragma unroll
    for (int cg = 0; cg < 2; ++cg) {
      int jloc = w * 32 + cg * 16 + cl;
      f32x4 dl = {0.f, 0.f, 0.f, 0.f};
#pragma unroll
      for (int kk = 0; kk < 4; ++kk) {
        bf16x8 a = *(const bf16x8*)&ztc[jloc * 256 + ((kk * 64 + lk * 16) ^ ((cl & 7) << 4))];
        dl = __builtin_amdgcn_mfma_f32_16x16x32_bf16(a, wbreg[kk], dl, 0, 0, 0);
      }
      if (cl < Hh) {
#pragma unroll
        for (int r = 0; r < 4; ++r)
          v[cg][r] = W_L * (dl[r] +
              bf2f(extb[(w * 32 + cg * 16 + lk * 4 + r) * 12 + cl]));
      } else {
#pragma unroll
        for (int r = 0; r < 4; ++r) v[cg][r] = -1e30f;
      }
    }

    // ---- Phase 2: per-wave softmax over 32 j (head = cl) ----
    float m_w = v[0][0];
#pragma unroll
    for (int cg = 0; cg < 2; ++cg)
#pragma unroll
      for (int r = 0; r < 4; ++r) m_w = fmaxf(m_w, v[cg][r]);
    m_w = fmaxf(m_w, __shfl_xor(m_w, 16));
    m_w = fmaxf(m_w, __shfl_xor(m_w, 32));

    float ps = 0.f;
#pragma unroll
    for (int cg = 0; cg < 2; ++cg) {
      int j = w * 32 + cg * 16 + lk * 4;           // local j
      ushort_t p0 = f2bf(__expf(v[cg][0] - m_w));
      ushort_t p1 = f2bf(__expf(v[cg][1] - m_w));
      ushort_t p2 = f2bf(__expf(v[cg][2] - m_w));
      ushort_t p3 = f2bf(__expf(v[cg][3] - m_w));
      ps += bf2f(p0) + bf2f(p1) + bf2f(p2) + bf2f(p3);
      uint2 d;
      d.x = (uint_t)p0 | ((uint_t)p1 << 16);
      d.y = (uint_t)p2 | ((uint_t)p3 << 16);
      *(uint2*)&pB[(cl * 512 + j * 2) ^ swz] = d;
    }
    ps += __shfl_xor(ps, 16);
    ps += __shfl_xor(ps, 32);
    if (lk == 0) { mb[w * 16 + cl] = m_w; lb[w * 16 + cl] = ps; }
    __syncthreads();                               // A

    if (tid < 16) {
      float m1 = mb[tid];
#pragma unroll
      for (int ww = 1; ww < 8; ++ww) m1 = fmaxf(m1, mb[ww * 16 + tid]);
      float Mold = Mrun[tid];
      float Mnew = fmaxf(Mold, m1);
      float Lh = 0.f;
#pragma unroll
      for (int ww = 0; ww < 8; ++ww)
        Lh += lb[ww * 16 + tid] * __expf(mb[ww * 16 + tid] - Mnew);
      L_run = L_run * __expf(Mold - Mnew) + Lh;
      Mv[tid] = Mnew;
      mb[tid] = __expf(Mold - Mnew);               // acc rescale factor (reuse mb)
      Mrun[tid] = Mnew;
    }
    __syncthreads();                               // B

    // ---- acc rescale by exp(M_old - M_new) (no-op at half 0: acc==0) ----
    if (half == 1) {
      float scr[4];
#pragma unroll
      for (int r = 0; r < 4; ++r) scr[r] = mb[lk * 4 + r];
#pragma unroll
      for (int n = 0; n < 5; ++n)
#pragma unroll
        for (int r = 0; r < 4; ++r) acc[n][r] *= scr[r];
    }

    // ---- Phase 3: rescale own P slice by exp(m_w - M_new) ----
    float sf = __expf(m_w - Mv[cl]);
#pragma unroll
    for (int q = 0; q < 2; ++q) {
      int j = w * 32 + lk * 8 + q * 4;
      uint_t off = (uint_t)(cl * 512 + j * 2) ^ swz;
      uint2 d = *(uint2*)&pB[off];
      ushort_t q0 = f2bf(bf2f((ushort_t)(d.x & 0xffff)) * sf);
      ushort_t q1 = f2bf(bf2f((ushort_t)(d.x >> 16)) * sf);
      ushort_t q2 = f2bf(bf2f((ushort_t)(d.y & 0xffff)) * sf);
      ushort_t q3 = f2bf(bf2f((ushort_t)(d.y >> 16)) * sf);
      d.x = (uint_t)q0 | ((uint_t)q1 << 16);
      d.y = (uint_t)q2 | ((uint_t)q3 << 16);
      *(uint2*)&pB[off] = d;
    }
    __syncthreads();                               // C

    // ---- Phase 4: attend; vfrag double-buffered ----
    bf16x8 vA[4], vB[4];
#define LOADV(buf, kk_) { \
    _Pragma("unroll") \
    for (int n = 1; n < 5; ++n) { \
      int t = w + n * 8; \
      if (t < 38) buf[n - 1] = *(const bf16x8*)(vfrag + \
          (((size_t)(t - 8) * 16 + (half * 8 + (kk_))) * 64 + l) * 8); \
    } }
#define COMPUTE(buf, kk_) { \
    int koff = (kk_) * 32 + lk * 8; \
    bf16x8 af = *(const bf16x8*)&pB[(cl * 512 + koff * 2) ^ swz]; \
    bf16x8 b0; \
    _Pragma("unroll") \
    for (int e = 0; e < 8; ++e) \
      b0[e] = *(const short*)&ztc[(koff + e) * 256 + ((w * 32 + cl * 2) ^ (e << 4))]; \
    acc[0] = __builtin_amdgcn_mfma_f32_16x16x32_bf16(af, b0, acc[0], 0, 0, 0); \
    _Pragma("unroll") \
    for (int n = 1; n < 5; ++n) { \
      int t = w + n * 8; \
      if (t < 38) acc[n] = __builtin_amdgcn_mfma_f32_16x16x32_bf16(af, buf[n - 1], acc[n], 0, 0, 0); \
    } }

    LOADV(vA, 0)
#pragma unroll
    for (int kk = 0; kk < 8; kk += 2) {
      LOADV(vB, kk + 1)
      COMPUTE(vA, kk)
      if (kk < 6) LOADV(vA, kk + 2)
      COMPUTE(vB, kk + 1)
    }
#undef LOADV
#undef COMPUTE
    __syncthreads();                               // D: ztc/pB reusable
  }

  // ---- epilogue: normalize by 1/L_run, write feat16 + invert/norm ----
  float* optg = (float*)extb;                      // extb dead; 288 f fits
  if (tid < 16) Mrun[tid] = (tid < Hh) ? 1.f / L_run : 0.f;   // Mrun := Lv
  __syncthreads();
  float rl[4];
#pragma unroll
  for (int r = 0; r < 4; ++r) rl[r] = Mrun[lk * 4 + r];
#pragma unroll
  for (int n = 0; n < 5; ++n) {
    int t = w + n * 8;
    if (t < 38) {
      if (t < 8) {
        int c = t * 16 + cl;
#pragma unroll
        for (int r = 0; r < 4; ++r) {
          int h = lk * 4 + r;
          if (h < Hh) Fi[h * CZ + c] = f2bf(acc[n][r] * rl[r]);
        }
      } else if (t < 20) {
        int h = t - 8;
        if (lk == (h >> 2)) Fi[1536 + h * CH + cl] = f2bf(acc[n][h & 3] * rl[h & 3]);
      } else {
        int cp = (t - 20) * 16 + cl;
        int h = cp / 24;
        if (lk == (h >> 2)) optg[cp] = acc[n][h & 3] * rl[h & 3];
      }
    }
  }
  __syncthreads();

  if (tid < 96) {
    int h = tid >> 3, p = tid & 7;
    int cp = h * 24 + p * 3;
    float g0 = optg[cp + 0] - trans[i * 3 + 0];
    float g1 = optg[cp + 1] - trans[i * 3 + 1];
    float g2 = optg[cp + 2] - trans[i * 3 + 2];
    const float* R = rot + i * 9;
    float ss = 0.f;
#pragma unroll
    for (int nn2 = 0; nn2 < 3; ++nn2) {
      float o = R[nn2] * g0 + R[3 + nn2] * g1 + R[6 + nn2] * g2;   // R^T (g - t)
      Fi[1728 + cp + nn2] = f2bf(o);
      ss += o * o;
    }
    Fi[2016 + h * 8 + p] = f2bf(sqrtf(ss + 1e-12f));
  }
}

// ====== K5: out = feat16 @ WfT^T + bf — split-K x2 + dual-acc ILP ===========
__global__ __launch_bounds__(256) void k_outm2(
    const ushort_t* __restrict__ feat16, const ushort_t* __restrict__ WfT,
    const float* __restrict__ bfv, float* __restrict__ out) {
  __shared__ f32x4 red[4][64];
  int ot = blockIdx.x;
  int ib = blockIdx.y;
  int tid = threadIdx.x;
  int l = tid & 63, w = tid >> 6;
  int cl = l & 15, lk = l >> 4;
  int i0 = ib * 32 + (w >> 1) * 16;
  int kw = w & 1;
  const ushort_t* arow = feat16 + (size_t)(i0 + cl) * FIN;
  const ushort_t* brow = WfT + (size_t)(ot * 16 + cl) * FIN;
  f32x4 accA = {0.f, 0.f, 0.f, 0.f}, accB = {0.f, 0.f, 0.f, 0.f};
  int k0 = kw * 33;
#pragma unroll 4
  for (int kk = k0; kk < k0 + 32; kk += 2) {
    bf16x8 a0 = *(const bf16x8*)(arow + kk * 32 + lk * 8);
    bf16x8 b0 = *(const bf16x8*)(brow + kk * 32 + lk * 8);
    accA = __builtin_amdgcn_mfma_f32_16x16x32_bf16(a0, b0, accA, 0, 0, 0);
    bf16x8 a1 = *(const bf16x8*)(arow + (kk + 1) * 32 + lk * 8);
    bf16x8 b1 = *(const bf16x8*)(brow + (kk + 1) * 32 + lk * 8);
    accB = __builtin_amdgcn_mfma_f32_16x16x32_bf16(a1, b1, accB, 0, 0, 0);
  }
  {
    int kk = k0 + 32;
    bf16x8 a = *(const bf16x8*)(arow + kk * 32 + lk * 8);
    bf16x8 b = *(const bf16x8*)(brow + kk * 32 + lk * 8);
    accA = __builtin_amdgcn_mfma_f32_16x16x32_bf16(a, b, accA, 0, 0, 0);
  }
#pragma unroll
  for (int r = 0; r < 4; ++r) accA[r] += accB[r];
  red[w][l] = accA;
  __syncthreads();
  if (kw == 0) {
    f32x4 s = red[w][l];
    f32x4 o = red[w + 1][l];
    float bias = bfv[ot * 16 + cl];
#pragma unroll
    for (int r = 0; r < 4; ++r)
      out[(size_t)(i0 + lk * 4 + r) * CS + ot * 16 + cl] = s[r] + o[r] + bias;
  }
}

// ============================ launcher ======================================
extern "C" void kernel_launch(void* const* d_in, const int* in_sizes, int n_in,
                              void* d_out, int out_size, void* d_ws, size_t ws_size,
                              hipStream_t stream) {
  const float* s_i   = (const float*)d_in[0];
  const float* z_ij  = (const float*)d_in[1];
  const float* rot   = (const float*)d_in[2];
  const float* trans = (const float*)d_in[3];
  const float* Wq    = (const float*)d_in[4];
  const float* Wk    = (const float*)d_in[5];
  const float* Wv    = (const float*)d_in[6];
  const float* Wqp   = (const float*)d_in[7];
  const float* Wkp   = (const float*)d_in[8];
  const float* Wvp   = (const float*)d_in[9];
  const float* Wb    = (const float*)d_in[10];
  const float* gamma = (const float*)d_in[11];
  const float* Wf    = (const float*)d_in[12];
  const float* bf    = (const float*)d_in[13];
  float* out = (float*)d_out;

  float* w = (float*)d_ws;
  float*    P     = w + OFF_P;
  float*    mq    = w + OFF_MQ;
  float*    mk    = w + OFF_MK;
  ushort_t* vT    = (ushort_t*)(w + OFF_VT);
  ushort_t* vpT   = (ushort_t*)(w + OFF_VPT);
  ushort_t* s16   = (ushort_t*)(w + OFF_S16);
  ushort_t* WcT   = (ushort_t*)(w + OFF_WCT);
  ushort_t* WfT   = (ushort_t*)(w + OFF_WFT);
  ushort_t* f16   = (ushort_t*)(w + OFF_F16);
  ushort_t* vfrag = (ushort_t*)(w + OFF_VFRAG);
  float*    ext   = w + OFF_EXT;
  ushort_t* ekb   = (ushort_t*)(w + OFF_EKB);
  ushort_t* eqb   = (ushort_t*)(w + OFF_EQB);
  ushort_t* wbf   = (ushort_t*)(w + OFF_WBF);

  k_conv<<<2049, 384, 0, stream>>>(s_i, Wq, Wk, Wv, Wqp, Wkp, Wvp, Wf, Wb,
                                   s16, WcT, WfT, wbf);
  k_projm<<<dim3(72, 32), 64, 0, stream>>>(s16, WcT, P);
  k_prep<<<96, 64, 0, stream>>>(P, rot, trans, gamma, eqb, ekb, mq, mk, vT, vpT);
  k_aux<<<1064, 768, 0, stream>>>(eqb, ekb, mk, ext, vT, vpT, vfrag);
  k_fused10<<<512, 512, 0, stream>>>(z_ij, wbf, ext, vfrag, rot, trans, f16);
  k_outm2<<<dim3(24, 16), 256, 0, stream>>>(f16, WfT, bf, out);
}

// Round 19
// 89.309 us; speedup vs baseline: 1.2810x; 1.2810x over previous
//
#include <hip/hip_runtime.h>
#include <hip/hip_bf16.h>
#include <math.h>

#define Nn    512
#define CS    384
#define CZ    128
#define CH    16
#define Hh    12
#define PQ    4
#define PV    8
#define NCOL  1152   // 192*3 + 144*2 + 288
#define FIN   2112

#define W_C   0.23570226039551584f   // sqrt(2/(9*4))
#define W_L   0.5773502691896258f    // sqrt(1/3)

typedef unsigned short ushort_t;
typedef unsigned int uint_t;
typedef __attribute__((ext_vector_type(8))) short bf16x8;
typedef __attribute__((ext_vector_type(4))) float f32x4;

// ---------------- workspace layout (float offsets) ----------------
#define OFF_P      0u
#define OFF_MQ     589824u
#define OFF_MK     595968u
#define OFF_VT     602112u      // v16T  [192][512] bf16
#define OFF_VPT    651264u      // vpgT  [288][512] bf16
#define OFF_S16    1830912u     // s bf16 [512][384]
#define OFF_WCT    1929216u     // WcatT bf16 [1152][384]
#define OFF_WFT    2150400u     // WfT bf16 [384][2112]
#define OFF_F16    2555904u     // feat bf16 [512][2112] (ends 3096576)
#define OFF_PP     3145728u     // partials [512][2][2048] f32 (ends 5242880)
#define OFF_VFRAG  5328896u     // vfrag bf16 [30][16][64][8]
#define OFF_EXT    5451776u     // ext f32 [12][512][512] (ends 8597504)
#define OFF_EKB    21755904u    // ekb bf16 [6144][32]
#define OFF_EQB    21854208u    // eqb bf16 [6144][32]
#define OFF_WBF    21952512u

__device__ inline ushort_t f2bf(float f) {
  __hip_bfloat16 h = __float2bfloat16(f);
  return *reinterpret_cast<ushort_t*>(&h);
}
__device__ inline float bf2f(ushort_t u) {
  unsigned int x = ((unsigned int)u) << 16;
  return __uint_as_float(x);
}

// ====== K0: fused converters: s16 | WcatT | WfT | wbf (one launch) ==========
__global__ __launch_bounds__(384) void k_conv(
    const float* __restrict__ s, const float* __restrict__ Wq,
    const float* __restrict__ Wk, const float* __restrict__ Wv,
    const float* __restrict__ Wqp, const float* __restrict__ Wkp,
    const float* __restrict__ Wvp, const float* __restrict__ Wf,
    const float* __restrict__ Wb,
    ushort_t* __restrict__ s16, ushort_t* __restrict__ WcatT,
    ushort_t* __restrict__ WfT, ushort_t* __restrict__ wbf) {
  int b = blockIdx.x;
  if (b < 512) {
    int idx = b * 384 + threadIdx.x;
    s16[idx] = f2bf(s[idx]);
  } else if (b < 1664) {
    int col = b - 512, k = threadIdx.x;
    float v;
    if      (col < 192)  v = Wq [k * 192 + col];
    else if (col < 384)  v = Wk [k * 192 + col - 192];
    else if (col < 576)  v = Wv [k * 192 + col - 384];
    else if (col < 720)  v = Wqp[k * 144 + col - 576];
    else if (col < 864)  v = Wkp[k * 144 + col - 720];
    else                 v = Wvp[k * 288 + col - 864];
    WcatT[(size_t)col * CS + k] = f2bf(v);
  } else if (b < 2048) {
    int o = b - 1664;
    for (int f = threadIdx.x; f < FIN; f += 384)
      WfT[(size_t)o * FIN + f] = f2bf(Wf[(size_t)f * CS + o]);
  } else {
    int t = threadIdx.x;
    if (t < 256) {
      int kk = t >> 6, l = t & 63;
      int h = l & 15, lk = l >> 4;
#pragma unroll
      for (int e = 0; e < 8; ++e) {
        int c = kk * 32 + lk * 8 + e;
        wbf[t * 8 + e] = (h < Hh) ? f2bf(Wb[c * Hh + h]) : (ushort_t)0;
      }
    }
  }
}

// ============ K1: proj via MFMA (dual-acc ILP): P = s16 @ WcatT^T ===========
__global__ __launch_bounds__(64) void k_projm(
    const ushort_t* __restrict__ s16, const ushort_t* __restrict__ WcatT,
    float* __restrict__ P) {
  int colt = blockIdx.x;
  int i0 = blockIdx.y * 16;
  int l = threadIdx.x;
  int cl = l & 15, lk = l >> 4;
  f32x4 accA = {0.f, 0.f, 0.f, 0.f}, accB = {0.f, 0.f, 0.f, 0.f};
  const ushort_t* arow = s16 + (size_t)(i0 + cl) * CS;
  const ushort_t* brow = WcatT + (size_t)(colt * 16 + cl) * CS;
#pragma unroll
  for (int kk = 0; kk < 12; kk += 2) {
    bf16x8 a0 = *(const bf16x8*)(arow + kk * 32 + lk * 8);
    bf16x8 b0 = *(const bf16x8*)(brow + kk * 32 + lk * 8);
    accA = __builtin_amdgcn_mfma_f32_16x16x32_bf16(a0, b0, accA, 0, 0, 0);
    bf16x8 a1 = *(const bf16x8*)(arow + (kk + 1) * 32 + lk * 8);
    bf16x8 b1 = *(const bf16x8*)(brow + (kk + 1) * 32 + lk * 8);
    accB = __builtin_amdgcn_mfma_f32_16x16x32_bf16(a1, b1, accB, 0, 0, 0);
  }
#pragma unroll
  for (int r = 0; r < 4; ++r)
    P[(size_t)(i0 + lk * 4 + r) * NCOL + colt * 16 + cl] = accA[r] + accB[r];
}

// ===== K1b: rigid transforms -> eqb/ekb bf16, mq/mk, vT, vpT ================
__global__ __launch_bounds__(64) void k_prep(
    const float* __restrict__ P, const float* __restrict__ rot,
    const float* __restrict__ trans, const float* __restrict__ gamma,
    ushort_t* __restrict__ eqb, ushort_t* __restrict__ ekb,
    float* __restrict__ mq, float* __restrict__ mk,
    ushort_t* __restrict__ vT, ushort_t* __restrict__ vpT) {
  int gid = blockIdx.x * 64 + threadIdx.x;        // < 6144
  int i = gid / Hh, h = gid % Hh;
  const float* Pi = P + (size_t)i * NCOL;
  float R[9], T[3];
#pragma unroll
  for (int m = 0; m < 9; ++m) R[m] = rot[i * 9 + m];
#pragma unroll
  for (int m = 0; m < 3; ++m) T[m] = trans[i * 3 + m];
  float cg = W_C * gamma[h];

  ushort_t* eq = eqb + (size_t)gid * 32;
  ushort_t* ek = ekb + (size_t)gid * 32;
#pragma unroll
  for (int d = 0; d < CH; ++d) eq[d] = f2bf(Pi[h * CH + d] * 0.25f);
#pragma unroll
  for (int d = 0; d < CH; ++d) ek[d] = f2bf(Pi[192 + h * CH + d]);
  float sq = 0.f, sk = 0.f;
#pragma unroll
  for (int p = 0; p < PQ; ++p) {
    float x = Pi[576 + h * 12 + p * 3 + 0];
    float y = Pi[576 + h * 12 + p * 3 + 1];
    float zc = Pi[576 + h * 12 + p * 3 + 2];
    float gx = R[0] * x + R[1] * y + R[2] * zc + T[0];
    float gy = R[3] * x + R[4] * y + R[5] * zc + T[1];
    float gz = R[6] * x + R[7] * y + R[8] * zc + T[2];
    eq[16 + p * 3 + 0] = f2bf(cg * gx);
    eq[16 + p * 3 + 1] = f2bf(cg * gy);
    eq[16 + p * 3 + 2] = f2bf(cg * gz);
    sq += gx * gx + gy * gy + gz * gz;
  }
#pragma unroll
  for (int p = 0; p < PQ; ++p) {
    float x = Pi[720 + h * 12 + p * 3 + 0];
    float y = Pi[720 + h * 12 + p * 3 + 1];
    float zc = Pi[720 + h * 12 + p * 3 + 2];
    float gx = R[0] * x + R[1] * y + R[2] * zc + T[0];
    float gy = R[3] * x + R[4] * y + R[5] * zc + T[1];
    float gz = R[6] * x + R[7] * y + R[8] * zc + T[2];
    ek[16 + p * 3 + 0] = f2bf(gx);
    ek[16 + p * 3 + 1] = f2bf(gy);
    ek[16 + p * 3 + 2] = f2bf(gz);
    sk += gx * gx + gy * gy + gz * gz;
  }
#pragma unroll
  for (int d = 28; d < 32; ++d) { eq[d] = 0; ek[d] = 0; }
  mq[gid] = -0.5f * cg * sq;
  mk[gid] = -0.5f * cg * sk;

#pragma unroll
  for (int d = 0; d < CH; ++d)
    vT[(size_t)(h * CH + d) * Nn + i] = f2bf(Pi[384 + h * CH + d]);
#pragma unroll
  for (int p = 0; p < PV; ++p) {
    float x = Pi[864 + h * 24 + p * 3 + 0];
    float y = Pi[864 + h * 24 + p * 3 + 1];
    float zc = Pi[864 + h * 24 + p * 3 + 2];
    vpT[(size_t)(h * 24 + p * 3 + 0) * Nn + i] = f2bf(R[0] * x + R[1] * y + R[2] * zc + T[0]);
    vpT[(size_t)(h * 24 + p * 3 + 1) * Nn + i] = f2bf(R[3] * x + R[4] * y + R[5] * zc + T[1]);
    vpT[(size_t)(h * 24 + p * 3 + 2) * Nn + i] = f2bf(R[6] * x + R[7] * y + R[8] * zc + T[2]);
  }
}

// ===== K1d: merged aux: ext (blocks 0..1023) | vfrag (blocks 1024..1063) ====
__global__ __launch_bounds__(768) void k_aux(
    const ushort_t* __restrict__ eqb, const ushort_t* __restrict__ ekb,
    const float* __restrict__ mk, float* __restrict__ ext,
    const ushort_t* __restrict__ vT, const ushort_t* __restrict__ vpT,
    ushort_t* __restrict__ vfrag) {
  int b = blockIdx.x, tid = threadIdx.x;
  if (b < 1024) {                                  // ext: 12 head-GEMMs
    int it = b >> 5, jt = b & 31;
    int l = tid & 63, h = tid >> 6;                // wave = head 0..11
    int cl = l & 15, lk = l >> 4;
    bf16x8 a = *(const bf16x8*)(eqb + ((size_t)(it * 16 + cl) * Hh + h) * 32 + lk * 8);
    bf16x8 bb = *(const bf16x8*)(ekb + ((size_t)(jt * 16 + cl) * Hh + h) * 32 + lk * 8);
    f32x4 dl = {0.f, 0.f, 0.f, 0.f};
    dl = __builtin_amdgcn_mfma_f32_16x16x32_bf16(a, bb, dl, 0, 0, 0);
    float mkv = mk[(jt * 16 + cl) * Hh + h];
    float* erow = ext + ((size_t)h * Nn + it * 16 + lk * 4) * Nn + jt * 16 + cl;
#pragma unroll
    for (int r = 0; r < 4; ++r) erow[(size_t)r * Nn] = dl[r] + mkv;
  } else {                                         // vfrag: 30720 items
    int flat = (b - 1024) * 768 + tid;
    if (flat < 30720) {
      int tt = flat >> 10;
      int r = flat & 1023;
      int jb = r >> 6, l = r & 63;
      int cl = l & 15, lk = l >> 4;
      const ushort_t* src = (tt < 12)
          ? vT  + (size_t)(tt * 16 + cl) * Nn
          : vpT + (size_t)((tt - 12) * 16 + cl) * Nn;
      bf16x8 v = *(const bf16x8*)(src + jb * 32 + lk * 8);
      *(bf16x8*)(vfrag + (((size_t)tt * 16 + jb) * 64 + l) * 8) = v;
    }
  }
}

// ======== K2: fused flash; PER-WAVE staging (no staging barrier), 3 barriers =
__global__ __launch_bounds__(512, 4) void k_fused9(
    const float* __restrict__ z, const ushort_t* __restrict__ wbf,
    const float* __restrict__ ext, const ushort_t* __restrict__ vfrag,
    float* __restrict__ pp) {
  __shared__ float smemf[20240];                   // 80960 B -> 2 blocks/CU
  char*     ztc  = (char*)smemf;                   // [256][128] bf16 swz (64KB)
  char*     pB   = (char*)smemf + 65536;           // [16][256] u16 swz (8KB)
  ushort_t* extb = (ushort_t*)((char*)smemf + 73728); // [256][12] bf16 (6KB)
  float*    mb   = smemf + 19968;                  // [8][16]
  float*    lb   = smemf + 20096;                  // [8][16]
  float*    Mv   = smemf + 20224;                  // [16]

  int i = blockIdx.x, half = blockIdx.y, tid = threadIdx.x;
  int l = tid & 63, w = tid >> 6;                  // 8 waves
  int cl = l & 15, lk = l >> 4;
  int j0b = half * 256;
  float* po = pp + ((size_t)i * 2 + half) * 2048;
  int swz = (cl & 7) << 4;

  // ---- per-wave staging: OWN 32 z-rows (16 f4/lane) + OWN ext slice ----
  const float4* zg4 = (const float4*)(z + ((size_t)i * Nn + j0b) * CZ);
  float4 xv0 = zg4[w * 1024 + 0 * 64 + l],  xv1 = zg4[w * 1024 + 1 * 64 + l];
  float4 xv2 = zg4[w * 1024 + 2 * 64 + l],  xv3 = zg4[w * 1024 + 3 * 64 + l];
  float4 xv4 = zg4[w * 1024 + 4 * 64 + l],  xv5 = zg4[w * 1024 + 5 * 64 + l];
  float4 xv6 = zg4[w * 1024 + 6 * 64 + l],  xv7 = zg4[w * 1024 + 7 * 64 + l];
  float4 xv8 = zg4[w * 1024 + 8 * 64 + l],  xv9 = zg4[w * 1024 + 9 * 64 + l];
  float4 xv10 = zg4[w * 1024 + 10 * 64 + l], xv11 = zg4[w * 1024 + 11 * 64 + l];
  float4 xv12 = zg4[w * 1024 + 12 * 64 + l], xv13 = zg4[w * 1024 + 13 * 64 + l];
  float4 xv14 = zg4[w * 1024 + 14 * 64 + l], xv15 = zg4[w * 1024 + 15 * 64 + l];
  float ev[6];
#pragma unroll
  for (int q = 0; q < 6; ++q) {
    int flat = q * 64 + l;                         // 0..383 = 12h x 32jl
    int eh = flat >> 5, ejl = flat & 31;
    ev[q] = ext[((size_t)eh * Nn + i) * Nn + j0b + w * 32 + ejl];
  }

#define STORE_ZT(it_, xv_) { \
    int idxl = (it_) * 64 + l; \
    int row = w * 32 + (idxl >> 5), c4 = idxl & 31; \
    uint2 pk; \
    pk.x = (uint_t)f2bf(xv_.x) | ((uint_t)f2bf(xv_.y) << 16); \
    pk.y = (uint_t)f2bf(xv_.z) | ((uint_t)f2bf(xv_.w) << 16); \
    *(uint2*)&ztc[row * 256 + ((c4 * 8) ^ ((row & 7) << 4))] = pk; }
  STORE_ZT(0, xv0)   STORE_ZT(1, xv1)   STORE_ZT(2, xv2)   STORE_ZT(3, xv3)
  STORE_ZT(4, xv4)   STORE_ZT(5, xv5)   STORE_ZT(6, xv6)   STORE_ZT(7, xv7)
  STORE_ZT(8, xv8)   STORE_ZT(9, xv9)   STORE_ZT(10, xv10) STORE_ZT(11, xv11)
  STORE_ZT(12, xv12) STORE_ZT(13, xv13) STORE_ZT(14, xv14) STORE_ZT(15, xv15)
#undef STORE_ZT
#pragma unroll
  for (int q = 0; q < 6; ++q) {
    int flat = q * 64 + l;
    extb[(w * 32 + (flat & 31)) * 12 + (flat >> 5)] = f2bf(ev[q]);
  }

  bf16x8 wbreg[4];
#pragma unroll
  for (int kk = 0; kk < 4; ++kk)
    wbreg[kk] = *(const bf16x8*)&wbf[(kk * 64 + l) * 8];

  // ---- Phase 1 (NO barrier: reads only own-wave rows) ----
  float v[2][4];
#pragma unroll
  for (int cg = 0; cg < 2; ++cg) {
    int jloc = w * 32 + cg * 16 + cl;
    f32x4 dl = {0.f, 0.f, 0.f, 0.f};
#pragma unroll
    for (int kk = 0; kk < 4; ++kk) {
      bf16x8 a = *(const bf16x8*)&ztc[jloc * 256 + ((kk * 64 + lk * 16) ^ ((cl & 7) << 4))];
      dl = __builtin_amdgcn_mfma_f32_16x16x32_bf16(a, wbreg[kk], dl, 0, 0, 0);
    }
    if (cl < Hh) {
#pragma unroll
      for (int r = 0; r < 4; ++r)
        v[cg][r] = W_L * (dl[r] +
            bf2f(extb[(w * 32 + cg * 16 + lk * 4 + r) * 12 + cl]));
    } else {
#pragma unroll
      for (int r = 0; r < 4; ++r) v[cg][r] = -1e30f;
    }
  }

  // ---- Phase 2: per-wave softmax over 32 j (head = cl) ----
  float m_w = v[0][0];
#pragma unroll
  for (int cg = 0; cg < 2; ++cg)
#pragma unroll
    for (int r = 0; r < 4; ++r) m_w = fmaxf(m_w, v[cg][r]);
  m_w = fmaxf(m_w, __shfl_xor(m_w, 16));
  m_w = fmaxf(m_w, __shfl_xor(m_w, 32));

  float ps = 0.f;
#pragma unroll
  for (int cg = 0; cg < 2; ++cg) {
    int j = w * 32 + cg * 16 + lk * 4;             // local j
    ushort_t p0 = f2bf(__expf(v[cg][0] - m_w));
    ushort_t p1 = f2bf(__expf(v[cg][1] - m_w));
    ushort_t p2 = f2bf(__expf(v[cg][2] - m_w));
    ushort_t p3 = f2bf(__expf(v[cg][3] - m_w));
    ps += bf2f(p0) + bf2f(p1) + bf2f(p2) + bf2f(p3);
    uint2 d;
    d.x = (uint_t)p0 | ((uint_t)p1 << 16);
    d.y = (uint_t)p2 | ((uint_t)p3 << 16);
    *(uint2*)&pB[(cl * 512 + j * 2) ^ swz] = d;
  }
  ps += __shfl_xor(ps, 16);
  ps += __shfl_xor(ps, 32);
  if (lk == 0) { mb[w * 16 + cl] = m_w; lb[w * 16 + cl] = ps; }
  __syncthreads();                                 // A (also: all ztc visible)

  if (tid < 16) {
    float M = mb[tid];
#pragma unroll
    for (int ww = 1; ww < 8; ++ww) M = fmaxf(M, mb[ww * 16 + tid]);
    float L = 0.f;
#pragma unroll
    for (int ww = 0; ww < 8; ++ww) L += lb[ww * 16 + tid] * __expf(mb[ww * 16 + tid] - M);
    Mv[tid] = M;
    po[2016 + tid] = M;
    po[2032 + tid] = L;
  }
  __syncthreads();                                 // B

  // ---- Phase 3: rescale own P slice by exp(m_w - M_block) ----
  float sf = __expf(m_w - Mv[cl]);
#pragma unroll
  for (int q = 0; q < 2; ++q) {
    int j = w * 32 + lk * 8 + q * 4;
    uint_t off = (uint_t)(cl * 512 + j * 2) ^ swz;
    uint2 d = *(uint2*)&pB[off];
    ushort_t q0 = f2bf(bf2f((ushort_t)(d.x & 0xffff)) * sf);
    ushort_t q1 = f2bf(bf2f((ushort_t)(d.x >> 16)) * sf);
    ushort_t q2 = f2bf(bf2f((ushort_t)(d.y & 0xffff)) * sf);
    ushort_t q3 = f2bf(bf2f((ushort_t)(d.y >> 16)) * sf);
    d.x = (uint_t)q0 | ((uint_t)q1 << 16);
    d.y = (uint_t)q2 | ((uint_t)q3 << 16);
    *(uint2*)&pB[off] = d;
  }
  __syncthreads();                                 // C

  // ---- Phase 4: attend; vfrag double-buffered ----
  f32x4 acc[5];
#pragma unroll
  for (int n = 0; n < 5; ++n) acc[n] = (f32x4){0.f, 0.f, 0.f, 0.f};
  bf16x8 vA[4], vB[4];

#define LOADV(buf, kk_) { \
    _Pragma("unroll") \
    for (int n = 1; n < 5; ++n) { \
      int t = w + n * 8; \
      if (t < 38) buf[n - 1] = *(const bf16x8*)(vfrag + \
          (((size_t)(t - 8) * 16 + (half * 8 + (kk_))) * 64 + l) * 8); \
    } }
#define COMPUTE(buf, kk_) { \
    int koff = (kk_) * 32 + lk * 8; \
    bf16x8 af = *(const bf16x8*)&pB[(cl * 512 + koff * 2) ^ swz]; \
    bf16x8 b0; \
    _Pragma("unroll") \
    for (int e = 0; e < 8; ++e) \
      b0[e] = *(const short*)&ztc[(koff + e) * 256 + ((w * 32 + cl * 2) ^ (e << 4))]; \
    acc[0] = __builtin_amdgcn_mfma_f32_16x16x32_bf16(af, b0, acc[0], 0, 0, 0); \
    _Pragma("unroll") \
    for (int n = 1; n < 5; ++n) { \
      int t = w + n * 8; \
      if (t < 38) acc[n] = __builtin_amdgcn_mfma_f32_16x16x32_bf16(af, buf[n - 1], acc[n], 0, 0, 0); \
    } }

  LOADV(vA, 0)
#pragma unroll
  for (int kk = 0; kk < 8; kk += 2) {
    LOADV(vB, kk + 1)
    COMPUTE(vA, kk)
    if (kk < 6) LOADV(vA, kk + 2)
    COMPUTE(vB, kk + 1)
  }
#undef LOADV
#undef COMPUTE

  // ---- store raw partial acc (no normalization) ----
#pragma unroll
  for (int n = 0; n < 5; ++n) {
    int t = w + n * 8;
    if (t < 38) {
      if (t < 8) {
        int c = t * 16 + cl;
#pragma unroll
        for (int r = 0; r < 4; ++r) {
          int h = lk * 4 + r;
          if (h < Hh) po[h * CZ + c] = acc[n][r];
        }
      } else if (t < 20) {
        int h = t - 8;
        if (lk == (h >> 2)) po[1536 + h * CH + cl] = acc[n][h & 3];
      } else {
        int cp = (t - 20) * 16 + cl;
        int h = cp / 24;
        if (lk == (h >> 2)) po[1728 + cp] = acc[n][h & 3];
      }
    }
  }
}

// ======== K3: merge halves + normalize + invert-apply + norm -> feat16 ======
__global__ __launch_bounds__(256) void k_merge(
    const float* __restrict__ pp, const float* __restrict__ rot,
    const float* __restrict__ trans, ushort_t* __restrict__ feat16) {
  __shared__ float a0s[16], a1s[16];
  __shared__ float optg[288];
  int i = blockIdx.x, tid = threadIdx.x;
  const float* p0 = pp + ((size_t)i * 2 + 0) * 2048;
  const float* p1 = pp + ((size_t)i * 2 + 1) * 2048;
  ushort_t* Fi = feat16 + (size_t)i * FIN;

  if (tid < 16) {
    float m0 = p0[2016 + tid], m1 = p1[2016 + tid];
    float M = fmaxf(m0, m1);
    float s0 = __expf(m0 - M), s1 = __expf(m1 - M);
    float L = p0[2032 + tid] * s0 + p1[2032 + tid] * s1;
    float inv = (tid < Hh) ? 1.f / L : 0.f;
    a0s[tid] = s0 * inv;
    a1s[tid] = s1 * inv;
  }
  __syncthreads();

  for (int idx = tid; idx < 1728; idx += 256) {
    int h = (idx < 1536) ? (idx >> 7) : ((idx - 1536) >> 4);
    Fi[idx] = f2bf(p0[idx] * a0s[h] + p1[idx] * a1s[h]);
  }
  for (int idx = tid; idx < 288; idx += 256) {
    int h = idx / 24;
    optg[idx] = p0[1728 + idx] * a0s[h] + p1[1728 + idx] * a1s[h];
  }
  __syncthreads();

  if (tid < 96) {
    int h = tid >> 3, p = tid & 7;
    int cp = h * 24 + p * 3;
    float g0 = optg[cp + 0] - trans[i * 3 + 0];
    float g1 = optg[cp + 1] - trans[i * 3 + 1];
    float g2 = optg[cp + 2] - trans[i * 3 + 2];
    const float* R = rot + i * 9;
    float ss = 0.f;
#pragma unroll
    for (int nn2 = 0; nn2 < 3; ++nn2) {
      float o = R[nn2] * g0 + R[3 + nn2] * g1 + R[6 + nn2] * g2;   // R^T (g - t)
      Fi[1728 + cp + nn2] = f2bf(o);
      ss += o * o;
    }
    Fi[2016 + h * 8 + p] = f2bf(sqrtf(ss + 1e-12f));
  }
}

// ====== K5: out = feat16 @ WfT^T + bf — split-K x2 + dual-acc ILP ===========
__global__ __launch_bounds__(256) void k_outm2(
    const ushort_t* __restrict__ feat16, const ushort_t* __restrict__ WfT,
    const float* __restrict__ bfv, float* __restrict__ out) {
  __shared__ f32x4 red[4][64];
  int ot = blockIdx.x;
  int ib = blockIdx.y;
  int tid = threadIdx.x;
  int l = tid & 63, w = tid >> 6;
  int cl = l & 15, lk = l >> 4;
  int i0 = ib * 32 + (w >> 1) * 16;
  int kw = w & 1;
  const ushort_t* arow = feat16 + (size_t)(i0 + cl) * FIN;
  const ushort_t* brow = WfT + (size_t)(ot * 16 + cl) * FIN;
  f32x4 accA = {0.f, 0.f, 0.f, 0.f}, accB = {0.f, 0.f, 0.f, 0.f};
  int k0 = kw * 33;
#pragma unroll 4
  for (int kk = k0; kk < k0 + 32; kk += 2) {
    bf16x8 a0 = *(const bf16x8*)(arow + kk * 32 + lk * 8);
    bf16x8 b0 = *(const bf16x8*)(brow + kk * 32 + lk * 8);
    accA = __builtin_amdgcn_mfma_f32_16x16x32_bf16(a0, b0, accA, 0, 0, 0);
    bf16x8 a1 = *(const bf16x8*)(arow + (kk + 1) * 32 + lk * 8);
    bf16x8 b1 = *(const bf16x8*)(brow + (kk + 1) * 32 + lk * 8);
    accB = __builtin_amdgcn_mfma_f32_16x16x32_bf16(a1, b1, accB, 0, 0, 0);
  }
  {
    int kk = k0 + 32;
    bf16x8 a = *(const bf16x8*)(arow + kk * 32 + lk * 8);
    bf16x8 b = *(const bf16x8*)(brow + kk * 32 + lk * 8);
    accA = __builtin_amdgcn_mfma_f32_16x16x32_bf16(a, b, accA, 0, 0, 0);
  }
#pragma unroll
  for (int r = 0; r < 4; ++r) accA[r] += accB[r];
  red[w][l] = accA;
  __syncthreads();
  if (kw == 0) {
    f32x4 s = red[w][l];
    f32x4 o = red[w + 1][l];
    float bias = bfv[ot * 16 + cl];
#pragma unroll
    for (int r = 0; r < 4; ++r)
      out[(size_t)(i0 + lk * 4 + r) * CS + ot * 16 + cl] = s[r] + o[r] + bias;
  }
}

// ============================ launcher ======================================
extern "C" void kernel_launch(void* const* d_in, const int* in_sizes, int n_in,
                              void* d_out, int out_size, void* d_ws, size_t ws_size,
                              hipStream_t stream) {
  const float* s_i   = (const float*)d_in[0];
  const float* z_ij  = (const float*)d_in[1];
  const float* rot   = (const float*)d_in[2];
  const float* trans = (const float*)d_in[3];
  const float* Wq    = (const float*)d_in[4];
  const float* Wk    = (const float*)d_in[5];
  const float* Wv    = (const float*)d_in[6];
  const float* Wqp   = (const float*)d_in[7];
  const float* Wkp   = (const float*)d_in[8];
  const float* Wvp   = (const float*)d_in[9];
  const float* Wb    = (const float*)d_in[10];
  const float* gamma = (const float*)d_in[11];
  const float* Wf    = (const float*)d_in[12];
  const float* bf    = (const float*)d_in[13];
  float* out = (float*)d_out;

  float* w = (float*)d_ws;
  float*    P     = w + OFF_P;
  float*    mq    = w + OFF_MQ;
  float*    mk    = w + OFF_MK;
  ushort_t* vT    = (ushort_t*)(w + OFF_VT);
  ushort_t* vpT   = (ushort_t*)(w + OFF_VPT);
  ushort_t* s16   = (ushort_t*)(w + OFF_S16);
  ushort_t* WcT   = (ushort_t*)(w + OFF_WCT);
  ushort_t* WfT   = (ushort_t*)(w + OFF_WFT);
  ushort_t* f16   = (ushort_t*)(w + OFF_F16);
  float*    pp    = w + OFF_PP;
  ushort_t* vfrag = (ushort_t*)(w + OFF_VFRAG);
  float*    ext   = w + OFF_EXT;
  ushort_t* ekb   = (ushort_t*)(w + OFF_EKB);
  ushort_t* eqb   = (ushort_t*)(w + OFF_EQB);
  ushort_t* wbf   = (ushort_t*)(w + OFF_WBF);

  k_conv<<<2049, 384, 0, stream>>>(s_i, Wq, Wk, Wv, Wqp, Wkp, Wvp, Wf, Wb,
                                   s16, WcT, WfT, wbf);
  k_projm<<<dim3(72, 32), 64, 0, stream>>>(s16, WcT, P);
  k_prep<<<96, 64, 0, stream>>>(P, rot, trans, gamma, eqb, ekb, mq, mk, vT, vpT);
  k_aux<<<1064, 768, 0, stream>>>(eqb, ekb, mk, ext, vT, vpT, vfrag);
  k_fused9<<<dim3(512, 2), 512, 0, stream>>>(z_ij, wbf, ext, vfrag, pp);
  k_merge<<<512, 256, 0, stream>>>(pp, rot, trans, f16);
  k_outm2<<<dim3(24, 16), 256, 0, stream>>>(f16, WfT, bf, out);
}

// Round 20
// 83.968 us; speedup vs baseline: 1.3625x; 1.0636x over previous
//
#include <hip/hip_runtime.h>
#include <hip/hip_bf16.h>
#include <math.h>

#define Nn    512
#define CS    384
#define CZ    128
#define CH    16
#define Hh    12
#define PQ    4
#define PV    8
#define NCOL  1152   // 192*3 + 144*2 + 288
#define FIN   2112

#define W_C   0.23570226039551584f   // sqrt(2/(9*4))
#define W_L   0.5773502691896258f    // sqrt(1/3)

typedef unsigned short ushort_t;
typedef unsigned int uint_t;
typedef __attribute__((ext_vector_type(8))) short bf16x8;
typedef __attribute__((ext_vector_type(4))) float f32x4;

// ---------------- workspace layout (float offsets) ----------------
#define OFF_P      0u
#define OFF_MQ     589824u
#define OFF_MK     595968u
#define OFF_VT     602112u      // v16T  [192][512] bf16
#define OFF_VPT    651264u      // vpgT  [288][512] bf16
#define OFF_S16    1830912u     // s bf16 [512][384]
#define OFF_WCT    1929216u     // WcatT bf16 [1152][384]
#define OFF_WFT    2150400u     // WfT bf16 [384][2112]
#define OFF_F16    2555904u     // feat bf16 [512][2112] (ends 3096576)
#define OFF_PP     3145728u     // partials [512][2][2048] f32 (ends 5242880)
#define OFF_VFRAG  5328896u     // vfrag bf16 [30][16][64][8]
#define OFF_EXT    5451776u     // ext f32 [12][512][512] (ends 8597504)
#define OFF_EKB    21755904u    // ekb bf16 [6144][32]
#define OFF_EQB    21854208u    // eqb bf16 [6144][32]
#define OFF_WBF    21952512u

__device__ inline ushort_t f2bf(float f) {
  __hip_bfloat16 h = __float2bfloat16(f);
  return *reinterpret_cast<ushort_t*>(&h);
}
__device__ inline float bf2f(ushort_t u) {
  unsigned int x = ((unsigned int)u) << 16;
  return __uint_as_float(x);
}

// ====== K0: fused converters; transposes via LDS tiles (coalesced both ways) =
// blocks: [0,512) s16 | [512,584) WcatT (6 arrays x 12 k-tiles) |
//         [584,650) WfT (66 f-tiles of 32) | 650 wbf
__global__ __launch_bounds__(384) void k_conv2(
    const float* __restrict__ s, const float* __restrict__ Wq,
    const float* __restrict__ Wk, const float* __restrict__ Wv,
    const float* __restrict__ Wqp, const float* __restrict__ Wkp,
    const float* __restrict__ Wvp, const float* __restrict__ Wf,
    const float* __restrict__ Wb,
    ushort_t* __restrict__ s16, ushort_t* __restrict__ WcatT,
    ushort_t* __restrict__ WfT, ushort_t* __restrict__ wbf) {
  __shared__ ushort_t lt[384 * 36];                // 27648 B, pad 36 vs 32
  int b = blockIdx.x, t = threadIdx.x;
  if (b < 512) {                                   // s16 (already coalesced)
    int idx = b * 384 + t;
    s16[idx] = f2bf(s[idx]);
    return;
  }
  if (b < 584) {                                   // WcatT: [k][col] -> [col][k]
    int bb = b - 512;
    int arr = bb / 12, kt = bb - arr * 12;         // k-tile of 32
    const float* W; int nc, cbase;
    if      (arr == 0) { W = Wq;  nc = 192; cbase = 0;   }
    else if (arr == 1) { W = Wk;  nc = 192; cbase = 192; }
    else if (arr == 2) { W = Wv;  nc = 192; cbase = 384; }
    else if (arr == 3) { W = Wqp; nc = 144; cbase = 576; }
    else if (arr == 4) { W = Wkp; nc = 144; cbase = 720; }
    else               { W = Wvp; nc = 288; cbase = 864; }
#pragma unroll 4
    for (int r = 0; r < 32; ++r)
      if (t < nc) lt[t * 36 + r] = f2bf(W[(size_t)(kt * 32 + r) * nc + t]);
    __syncthreads();
    int g = t >> 5, ss = t & 31;
    for (int cc = g; cc < nc; cc += 12)
      WcatT[(size_t)(cbase + cc) * CS + kt * 32 + ss] = lt[cc * 36 + ss];
    return;
  }
  if (b < 650) {                                   // WfT: [f][o] -> [o][f]
    int bb = b - 584;                              // f-tile of 32
#pragma unroll 4
    for (int r = 0; r < 32; ++r)
      lt[t * 36 + r] = f2bf(Wf[(size_t)(bb * 32 + r) * CS + t]);
    __syncthreads();
    int g = t >> 5, ss = t & 31;
#pragma unroll 4
    for (int jj = 0; jj < 32; ++jj) {
      int o = g * 32 + jj;
      WfT[(size_t)o * FIN + bb * 32 + ss] = lt[o * 36 + ss];
    }
    return;
  }
  // wbf fragments (b == 650)
  if (t < 256) {
    int kk = t >> 6, l = t & 63;
    int h = l & 15, lk = l >> 4;
#pragma unroll
    for (int e = 0; e < 8; ++e) {
      int c = kk * 32 + lk * 8 + e;
      wbf[t * 8 + e] = (h < Hh) ? f2bf(Wb[c * Hh + h]) : (ushort_t)0;
    }
  }
}

// ============ K1: proj via MFMA (dual-acc ILP): P = s16 @ WcatT^T ===========
__global__ __launch_bounds__(64) void k_projm(
    const ushort_t* __restrict__ s16, const ushort_t* __restrict__ WcatT,
    float* __restrict__ P) {
  int colt = blockIdx.x;
  int i0 = blockIdx.y * 16;
  int l = threadIdx.x;
  int cl = l & 15, lk = l >> 4;
  f32x4 accA = {0.f, 0.f, 0.f, 0.f}, accB = {0.f, 0.f, 0.f, 0.f};
  const ushort_t* arow = s16 + (size_t)(i0 + cl) * CS;
  const ushort_t* brow = WcatT + (size_t)(colt * 16 + cl) * CS;
#pragma unroll
  for (int kk = 0; kk < 12; kk += 2) {
    bf16x8 a0 = *(const bf16x8*)(arow + kk * 32 + lk * 8);
    bf16x8 b0 = *(const bf16x8*)(brow + kk * 32 + lk * 8);
    accA = __builtin_amdgcn_mfma_f32_16x16x32_bf16(a0, b0, accA, 0, 0, 0);
    bf16x8 a1 = *(const bf16x8*)(arow + (kk + 1) * 32 + lk * 8);
    bf16x8 b1 = *(const bf16x8*)(brow + (kk + 1) * 32 + lk * 8);
    accB = __builtin_amdgcn_mfma_f32_16x16x32_bf16(a1, b1, accB, 0, 0, 0);
  }
#pragma unroll
  for (int r = 0; r < 4; ++r)
    P[(size_t)(i0 + lk * 4 + r) * NCOL + colt * 16 + cl] = accA[r] + accB[r];
}

// ===== K1b: rigid transforms -> eqb/ekb bf16, mq/mk, vT, vpT ================
__global__ __launch_bounds__(64) void k_prep(
    const float* __restrict__ P, const float* __restrict__ rot,
    const float* __restrict__ trans, const float* __restrict__ gamma,
    ushort_t* __restrict__ eqb, ushort_t* __restrict__ ekb,
    float* __restrict__ mq, float* __restrict__ mk,
    ushort_t* __restrict__ vT, ushort_t* __restrict__ vpT) {
  int gid = blockIdx.x * 64 + threadIdx.x;        // < 6144
  int i = gid / Hh, h = gid % Hh;
  const float* Pi = P + (size_t)i * NCOL;
  float R[9], T[3];
#pragma unroll
  for (int m = 0; m < 9; ++m) R[m] = rot[i * 9 + m];
#pragma unroll
  for (int m = 0; m < 3; ++m) T[m] = trans[i * 3 + m];
  float cg = W_C * gamma[h];

  ushort_t* eq = eqb + (size_t)gid * 32;
  ushort_t* ek = ekb + (size_t)gid * 32;
#pragma unroll
  for (int d = 0; d < CH; ++d) eq[d] = f2bf(Pi[h * CH + d] * 0.25f);
#pragma unroll
  for (int d = 0; d < CH; ++d) ek[d] = f2bf(Pi[192 + h * CH + d]);
  float sq = 0.f, sk = 0.f;
#pragma unroll
  for (int p = 0; p < PQ; ++p) {
    float x = Pi[576 + h * 12 + p * 3 + 0];
    float y = Pi[576 + h * 12 + p * 3 + 1];
    float zc = Pi[576 + h * 12 + p * 3 + 2];
    float gx = R[0] * x + R[1] * y + R[2] * zc + T[0];
    float gy = R[3] * x + R[4] * y + R[5] * zc + T[1];
    float gz = R[6] * x + R[7] * y + R[8] * zc + T[2];
    eq[16 + p * 3 + 0] = f2bf(cg * gx);
    eq[16 + p * 3 + 1] = f2bf(cg * gy);
    eq[16 + p * 3 + 2] = f2bf(cg * gz);
    sq += gx * gx + gy * gy + gz * gz;
  }
#pragma unroll
  for (int p = 0; p < PQ; ++p) {
    float x = Pi[720 + h * 12 + p * 3 + 0];
    float y = Pi[720 + h * 12 + p * 3 + 1];
    float zc = Pi[720 + h * 12 + p * 3 + 2];
    float gx = R[0] * x + R[1] * y + R[2] * zc + T[0];
    float gy = R[3] * x + R[4] * y + R[5] * zc + T[1];
    float gz = R[6] * x + R[7] * y + R[8] * zc + T[2];
    ek[16 + p * 3 + 0] = f2bf(gx);
    ek[16 + p * 3 + 1] = f2bf(gy);
    ek[16 + p * 3 + 2] = f2bf(gz);
    sk += gx * gx + gy * gy + gz * gz;
  }
#pragma unroll
  for (int d = 28; d < 32; ++d) { eq[d] = 0; ek[d] = 0; }
  mq[gid] = -0.5f * cg * sq;
  mk[gid] = -0.5f * cg * sk;

#pragma unroll
  for (int d = 0; d < CH; ++d)
    vT[(size_t)(h * CH + d) * Nn + i] = f2bf(Pi[384 + h * CH + d]);
#pragma unroll
  for (int p = 0; p < PV; ++p) {
    float x = Pi[864 + h * 24 + p * 3 + 0];
    float y = Pi[864 + h * 24 + p * 3 + 1];
    float zc = Pi[864 + h * 24 + p * 3 + 2];
    vpT[(size_t)(h * 24 + p * 3 + 0) * Nn + i] = f2bf(R[0] * x + R[1] * y + R[2] * zc + T[0]);
    vpT[(size_t)(h * 24 + p * 3 + 1) * Nn + i] = f2bf(R[3] * x + R[4] * y + R[5] * zc + T[1]);
    vpT[(size_t)(h * 24 + p * 3 + 2) * Nn + i] = f2bf(R[6] * x + R[7] * y + R[8] * zc + T[2]);
  }
}

// ===== K1d: merged aux: ext (blocks 0..1023) | vfrag (blocks 1024..1063) ====
__global__ __launch_bounds__(768) void k_aux(
    const ushort_t* __restrict__ eqb, const ushort_t* __restrict__ ekb,
    const float* __restrict__ mk, float* __restrict__ ext,
    const ushort_t* __restrict__ vT, const ushort_t* __restrict__ vpT,
    ushort_t* __restrict__ vfrag) {
  int b = blockIdx.x, tid = threadIdx.x;
  if (b < 1024) {                                  // ext: 12 head-GEMMs
    int it = b >> 5, jt = b & 31;
    int l = tid & 63, h = tid >> 6;                // wave = head 0..11
    int cl = l & 15, lk = l >> 4;
    bf16x8 a = *(const bf16x8*)(eqb + ((size_t)(it * 16 + cl) * Hh + h) * 32 + lk * 8);
    bf16x8 bb = *(const bf16x8*)(ekb + ((size_t)(jt * 16 + cl) * Hh + h) * 32 + lk * 8);
    f32x4 dl = {0.f, 0.f, 0.f, 0.f};
    dl = __builtin_amdgcn_mfma_f32_16x16x32_bf16(a, bb, dl, 0, 0, 0);
    float mkv = mk[(jt * 16 + cl) * Hh + h];
    float* erow = ext + ((size_t)h * Nn + it * 16 + lk * 4) * Nn + jt * 16 + cl;
#pragma unroll
    for (int r = 0; r < 4; ++r) erow[(size_t)r * Nn] = dl[r] + mkv;
  } else {                                         // vfrag: 30720 items
    int flat = (b - 1024) * 768 + tid;
    if (flat < 30720) {
      int tt = flat >> 10;
      int r = flat & 1023;
      int jb = r >> 6, l = r & 63;
      int cl = l & 15, lk = l >> 4;
      const ushort_t* src = (tt < 12)
          ? vT  + (size_t)(tt * 16 + cl) * Nn
          : vpT + (size_t)((tt - 12) * 16 + cl) * Nn;
      bf16x8 v = *(const bf16x8*)(src + jb * 32 + lk * 8);
      *(bf16x8*)(vfrag + (((size_t)tt * 16 + jb) * 64 + l) * 8) = v;
    }
  }
}

// ======== K2: fused flash; PER-WAVE staging (no staging barrier), 3 barriers =
__global__ __launch_bounds__(512, 4) void k_fused9(
    const float* __restrict__ z, const ushort_t* __restrict__ wbf,
    const float* __restrict__ ext, const ushort_t* __restrict__ vfrag,
    float* __restrict__ pp) {
  __shared__ float smemf[20240];                   // 80960 B -> 2 blocks/CU
  char*     ztc  = (char*)smemf;                   // [256][128] bf16 swz (64KB)
  char*     pB   = (char*)smemf + 65536;           // [16][256] u16 swz (8KB)
  ushort_t* extb = (ushort_t*)((char*)smemf + 73728); // [256][12] bf16 (6KB)
  float*    mb   = smemf + 19968;                  // [8][16]
  float*    lb   = smemf + 20096;                  // [8][16]
  float*    Mv   = smemf + 20224;                  // [16]

  int i = blockIdx.x, half = blockIdx.y, tid = threadIdx.x;
  int l = tid & 63, w = tid >> 6;                  // 8 waves
  int cl = l & 15, lk = l >> 4;
  int j0b = half * 256;
  float* po = pp + ((size_t)i * 2 + half) * 2048;
  int swz = (cl & 7) << 4;

  // ---- per-wave staging: OWN 32 z-rows (16 f4/lane) + OWN ext slice ----
  const float4* zg4 = (const float4*)(z + ((size_t)i * Nn + j0b) * CZ);
  float4 xv0 = zg4[w * 1024 + 0 * 64 + l],  xv1 = zg4[w * 1024 + 1 * 64 + l];
  float4 xv2 = zg4[w * 1024 + 2 * 64 + l],  xv3 = zg4[w * 1024 + 3 * 64 + l];
  float4 xv4 = zg4[w * 1024 + 4 * 64 + l],  xv5 = zg4[w * 1024 + 5 * 64 + l];
  float4 xv6 = zg4[w * 1024 + 6 * 64 + l],  xv7 = zg4[w * 1024 + 7 * 64 + l];
  float4 xv8 = zg4[w * 1024 + 8 * 64 + l],  xv9 = zg4[w * 1024 + 9 * 64 + l];
  float4 xv10 = zg4[w * 1024 + 10 * 64 + l], xv11 = zg4[w * 1024 + 11 * 64 + l];
  float4 xv12 = zg4[w * 1024 + 12 * 64 + l], xv13 = zg4[w * 1024 + 13 * 64 + l];
  float4 xv14 = zg4[w * 1024 + 14 * 64 + l], xv15 = zg4[w * 1024 + 15 * 64 + l];
  float ev[6];
#pragma unroll
  for (int q = 0; q < 6; ++q) {
    int flat = q * 64 + l;                         // 0..383 = 12h x 32jl
    int eh = flat >> 5, ejl = flat & 31;
    ev[q] = ext[((size_t)eh * Nn + i) * Nn + j0b + w * 32 + ejl];
  }

#define STORE_ZT(it_, xv_) { \
    int idxl = (it_) * 64 + l; \
    int row = w * 32 + (idxl >> 5), c4 = idxl & 31; \
    uint2 pk; \
    pk.x = (uint_t)f2bf(xv_.x) | ((uint_t)f2bf(xv_.y) << 16); \
    pk.y = (uint_t)f2bf(xv_.z) | ((uint_t)f2bf(xv_.w) << 16); \
    *(uint2*)&ztc[row * 256 + ((c4 * 8) ^ ((row & 7) << 4))] = pk; }
  STORE_ZT(0, xv0)   STORE_ZT(1, xv1)   STORE_ZT(2, xv2)   STORE_ZT(3, xv3)
  STORE_ZT(4, xv4)   STORE_ZT(5, xv5)   STORE_ZT(6, xv6)   STORE_ZT(7, xv7)
  STORE_ZT(8, xv8)   STORE_ZT(9, xv9)   STORE_ZT(10, xv10) STORE_ZT(11, xv11)
  STORE_ZT(12, xv12) STORE_ZT(13, xv13) STORE_ZT(14, xv14) STORE_ZT(15, xv15)
#undef STORE_ZT
#pragma unroll
  for (int q = 0; q < 6; ++q) {
    int flat = q * 64 + l;
    extb[(w * 32 + (flat & 31)) * 12 + (flat >> 5)] = f2bf(ev[q]);
  }

  bf16x8 wbreg[4];
#pragma unroll
  for (int kk = 0; kk < 4; ++kk)
    wbreg[kk] = *(const bf16x8*)&wbf[(kk * 64 + l) * 8];

  // ---- Phase 1 (NO barrier: reads only own-wave rows) ----
  float v[2][4];
#pragma unroll
  for (int cg = 0; cg < 2; ++cg) {
    int jloc = w * 32 + cg * 16 + cl;
    f32x4 dl = {0.f, 0.f, 0.f, 0.f};
#pragma unroll
    for (int kk = 0; kk < 4; ++kk) {
      bf16x8 a = *(const bf16x8*)&ztc[jloc * 256 + ((kk * 64 + lk * 16) ^ ((cl & 7) << 4))];
      dl = __builtin_amdgcn_mfma_f32_16x16x32_bf16(a, wbreg[kk], dl, 0, 0, 0);
    }
    if (cl < Hh) {
#pragma unroll
      for (int r = 0; r < 4; ++r)
        v[cg][r] = W_L * (dl[r] +
            bf2f(extb[(w * 32 + cg * 16 + lk * 4 + r) * 12 + cl]));
    } else {
#pragma unroll
      for (int r = 0; r < 4; ++r) v[cg][r] = -1e30f;
    }
  }

  // ---- Phase 2: per-wave softmax over 32 j (head = cl) ----
  float m_w = v[0][0];
#pragma unroll
  for (int cg = 0; cg < 2; ++cg)
#pragma unroll
    for (int r = 0; r < 4; ++r) m_w = fmaxf(m_w, v[cg][r]);
  m_w = fmaxf(m_w, __shfl_xor(m_w, 16));
  m_w = fmaxf(m_w, __shfl_xor(m_w, 32));

  float ps = 0.f;
#pragma unroll
  for (int cg = 0; cg < 2; ++cg) {
    int j = w * 32 + cg * 16 + lk * 4;             // local j
    ushort_t p0 = f2bf(__expf(v[cg][0] - m_w));
    ushort_t p1 = f2bf(__expf(v[cg][1] - m_w));
    ushort_t p2 = f2bf(__expf(v[cg][2] - m_w));
    ushort_t p3 = f2bf(__expf(v[cg][3] - m_w));
    ps += bf2f(p0) + bf2f(p1) + bf2f(p2) + bf2f(p3);
    uint2 d;
    d.x = (uint_t)p0 | ((uint_t)p1 << 16);
    d.y = (uint_t)p2 | ((uint_t)p3 << 16);
    *(uint2*)&pB[(cl * 512 + j * 2) ^ swz] = d;
  }
  ps += __shfl_xor(ps, 16);
  ps += __shfl_xor(ps, 32);
  if (lk == 0) { mb[w * 16 + cl] = m_w; lb[w * 16 + cl] = ps; }
  __syncthreads();                                 // A (also: all ztc visible)

  if (tid < 16) {
    float M = mb[tid];
#pragma unroll
    for (int ww = 1; ww < 8; ++ww) M = fmaxf(M, mb[ww * 16 + tid]);
    float L = 0.f;
#pragma unroll
    for (int ww = 0; ww < 8; ++ww) L += lb[ww * 16 + tid] * __expf(mb[ww * 16 + tid] - M);
    Mv[tid] = M;
    po[2016 + tid] = M;
    po[2032 + tid] = L;
  }
  __syncthreads();                                 // B

  // ---- Phase 3: rescale own P slice by exp(m_w - M_block) ----
  float sf = __expf(m_w - Mv[cl]);
#pragma unroll
  for (int q = 0; q < 2; ++q) {
    int j = w * 32 + lk * 8 + q * 4;
    uint_t off = (uint_t)(cl * 512 + j * 2) ^ swz;
    uint2 d = *(uint2*)&pB[off];
    ushort_t q0 = f2bf(bf2f((ushort_t)(d.x & 0xffff)) * sf);
    ushort_t q1 = f2bf(bf2f((ushort_t)(d.x >> 16)) * sf);
    ushort_t q2 = f2bf(bf2f((ushort_t)(d.y & 0xffff)) * sf);
    ushort_t q3 = f2bf(bf2f((ushort_t)(d.y >> 16)) * sf);
    d.x = (uint_t)q0 | ((uint_t)q1 << 16);
    d.y = (uint_t)q2 | ((uint_t)q3 << 16);
    *(uint2*)&pB[off] = d;
  }
  __syncthreads();                                 // C

  // ---- Phase 4: attend; vfrag double-buffered ----
  f32x4 acc[5];
#pragma unroll
  for (int n = 0; n < 5; ++n) acc[n] = (f32x4){0.f, 0.f, 0.f, 0.f};
  bf16x8 vA[4], vB[4];

#define LOADV(buf, kk_) { \
    _Pragma("unroll") \
    for (int n = 1; n < 5; ++n) { \
      int t = w + n * 8; \
      if (t < 38) buf[n - 1] = *(const bf16x8*)(vfrag + \
          (((size_t)(t - 8) * 16 + (half * 8 + (kk_))) * 64 + l) * 8); \
    } }
#define COMPUTE(buf, kk_) { \
    int koff = (kk_) * 32 + lk * 8; \
    bf16x8 af = *(const bf16x8*)&pB[(cl * 512 + koff * 2) ^ swz]; \
    bf16x8 b0; \
    _Pragma("unroll") \
    for (int e = 0; e < 8; ++e) \
      b0[e] = *(const short*)&ztc[(koff + e) * 256 + ((w * 32 + cl * 2) ^ (e << 4))]; \
    acc[0] = __builtin_amdgcn_mfma_f32_16x16x32_bf16(af, b0, acc[0], 0, 0, 0); \
    _Pragma("unroll") \
    for (int n = 1; n < 5; ++n) { \
      int t = w + n * 8; \
      if (t < 38) acc[n] = __builtin_amdgcn_mfma_f32_16x16x32_bf16(af, buf[n - 1], acc[n], 0, 0, 0); \
    } }

  LOADV(vA, 0)
#pragma unroll
  for (int kk = 0; kk < 8; kk += 2) {
    LOADV(vB, kk + 1)
    COMPUTE(vA, kk)
    if (kk < 6) LOADV(vA, kk + 2)
    COMPUTE(vB, kk + 1)
  }
#undef LOADV
#undef COMPUTE

  // ---- store raw partial acc (no normalization) ----
#pragma unroll
  for (int n = 0; n < 5; ++n) {
    int t = w + n * 8;
    if (t < 38) {
      if (t < 8) {
        int c = t * 16 + cl;
#pragma unroll
        for (int r = 0; r < 4; ++r) {
          int h = lk * 4 + r;
          if (h < Hh) po[h * CZ + c] = acc[n][r];
        }
      } else if (t < 20) {
        int h = t - 8;
        if (lk == (h >> 2)) po[1536 + h * CH + cl] = acc[n][h & 3];
      } else {
        int cp = (t - 20) * 16 + cl;
        int h = cp / 24;
        if (lk == (h >> 2)) po[1728 + cp] = acc[n][h & 3];
      }
    }
  }
}

// ======== K3: merge halves + normalize + invert-apply + norm -> feat16 ======
__global__ __launch_bounds__(256) void k_merge(
    const float* __restrict__ pp, const float* __restrict__ rot,
    const float* __restrict__ trans, ushort_t* __restrict__ feat16) {
  __shared__ float a0s[16], a1s[16];
  __shared__ float optg[288];
  int i = blockIdx.x, tid = threadIdx.x;
  const float* p0 = pp + ((size_t)i * 2 + 0) * 2048;
  const float* p1 = pp + ((size_t)i * 2 + 1) * 2048;
  ushort_t* Fi = feat16 + (size_t)i * FIN;

  if (tid < 16) {
    float m0 = p0[2016 + tid], m1 = p1[2016 + tid];
    float M = fmaxf(m0, m1);
    float s0 = __expf(m0 - M), s1 = __expf(m1 - M);
    float L = p0[2032 + tid] * s0 + p1[2032 + tid] * s1;
    float inv = (tid < Hh) ? 1.f / L : 0.f;
    a0s[tid] = s0 * inv;
    a1s[tid] = s1 * inv;
  }
  __syncthreads();

  for (int idx = tid; idx < 1728; idx += 256) {
    int h = (idx < 1536) ? (idx >> 7) : ((idx - 1536) >> 4);
    Fi[idx] = f2bf(p0[idx] * a0s[h] + p1[idx] * a1s[h]);
  }
  for (int idx = tid; idx < 288; idx += 256) {
    int h = idx / 24;
    optg[idx] = p0[1728 + idx] * a0s[h] + p1[1728 + idx] * a1s[h];
  }
  __syncthreads();

  if (tid < 96) {
    int h = tid >> 3, p = tid & 7;
    int cp = h * 24 + p * 3;
    float g0 = optg[cp + 0] - trans[i * 3 + 0];
    float g1 = optg[cp + 1] - trans[i * 3 + 1];
    float g2 = optg[cp + 2] - trans[i * 3 + 2];
    const float* R = rot + i * 9;
    float ss = 0.f;
#pragma unroll
    for (int nn2 = 0; nn2 < 3; ++nn2) {
      float o = R[nn2] * g0 + R[3 + nn2] * g1 + R[6 + nn2] * g2;   // R^T (g - t)
      Fi[1728 + cp + nn2] = f2bf(o);
      ss += o * o;
    }
    Fi[2016 + h * 8 + p] = f2bf(sqrtf(ss + 1e-12f));
  }
}

// ====== K5: out = feat16 @ WfT^T + bf — split-K x2 + dual-acc ILP ===========
__global__ __launch_bounds__(256) void k_outm2(
    const ushort_t* __restrict__ feat16, const ushort_t* __restrict__ WfT,
    const float* __restrict__ bfv, float* __restrict__ out) {
  __shared__ f32x4 red[4][64];
  int ot = blockIdx.x;
  int ib = blockIdx.y;
  int tid = threadIdx.x;
  int l = tid & 63, w = tid >> 6;
  int cl = l & 15, lk = l >> 4;
  int i0 = ib * 32 + (w >> 1) * 16;
  int kw = w & 1;
  const ushort_t* arow = feat16 + (size_t)(i0 + cl) * FIN;
  const ushort_t* brow = WfT + (size_t)(ot * 16 + cl) * FIN;
  f32x4 accA = {0.f, 0.f, 0.f, 0.f}, accB = {0.f, 0.f, 0.f, 0.f};
  int k0 = kw * 33;
#pragma unroll 4
  for (int kk = k0; kk < k0 + 32; kk += 2) {
    bf16x8 a0 = *(const bf16x8*)(arow + kk * 32 + lk * 8);
    bf16x8 b0 = *(const bf16x8*)(brow + kk * 32 + lk * 8);
    accA = __builtin_amdgcn_mfma_f32_16x16x32_bf16(a0, b0, accA, 0, 0, 0);
    bf16x8 a1 = *(const bf16x8*)(arow + (kk + 1) * 32 + lk * 8);
    bf16x8 b1 = *(const bf16x8*)(brow + (kk + 1) * 32 + lk * 8);
    accB = __builtin_amdgcn_mfma_f32_16x16x32_bf16(a1, b1, accB, 0, 0, 0);
  }
  {
    int kk = k0 + 32;
    bf16x8 a = *(const bf16x8*)(arow + kk * 32 + lk * 8);
    bf16x8 b = *(const bf16x8*)(brow + kk * 32 + lk * 8);
    accA = __builtin_amdgcn_mfma_f32_16x16x32_bf16(a, b, accA, 0, 0, 0);
  }
#pragma unroll
  for (int r = 0; r < 4; ++r) accA[r] += accB[r];
  red[w][l] = accA;
  __syncthreads();
  if (kw == 0) {
    f32x4 s = red[w][l];
    f32x4 o = red[w + 1][l];
    float bias = bfv[ot * 16 + cl];
#pragma unroll
    for (int r = 0; r < 4; ++r)
      out[(size_t)(i0 + lk * 4 + r) * CS + ot * 16 + cl] = s[r] + o[r] + bias;
  }
}

// ============================ launcher ======================================
extern "C" void kernel_launch(void* const* d_in, const int* in_sizes, int n_in,
                              void* d_out, int out_size, void* d_ws, size_t ws_size,
                              hipStream_t stream) {
  const float* s_i   = (const float*)d_in[0];
  const float* z_ij  = (const float*)d_in[1];
  const float* rot   = (const float*)d_in[2];
  const float* trans = (const float*)d_in[3];
  const float* Wq    = (const float*)d_in[4];
  const float* Wk    = (const float*)d_in[5];
  const float* Wv    = (const float*)d_in[6];
  const float* Wqp   = (const float*)d_in[7];
  const float* Wkp   = (const float*)d_in[8];
  const float* Wvp   = (const float*)d_in[9];
  const float* Wb    = (const float*)d_in[10];
  const float* gamma = (const float*)d_in[11];
  const float* Wf    = (const float*)d_in[12];
  const float* bf    = (const float*)d_in[13];
  float* out = (float*)d_out;

  float* w = (float*)d_ws;
  float*    P     = w + OFF_P;
  float*    mq    = w + OFF_MQ;
  float*    mk    = w + OFF_MK;
  ushort_t* vT    = (ushort_t*)(w + OFF_VT);
  ushort_t* vpT   = (ushort_t*)(w + OFF_VPT);
  ushort_t* s16   = (ushort_t*)(w + OFF_S16);
  ushort_t* WcT   = (ushort_t*)(w + OFF_WCT);
  ushort_t* WfT   = (ushort_t*)(w + OFF_WFT);
  ushort_t* f16   = (ushort_t*)(w + OFF_F16);
  float*    pp    = w + OFF_PP;
  ushort_t* vfrag = (ushort_t*)(w + OFF_VFRAG);
  float*    ext   = w + OFF_EXT;
  ushort_t* ekb   = (ushort_t*)(w + OFF_EKB);
  ushort_t* eqb   = (ushort_t*)(w + OFF_EQB);
  ushort_t* wbf   = (ushort_t*)(w + OFF_WBF);

  k_conv2<<<651, 384, 0, stream>>>(s_i, Wq, Wk, Wv, Wqp, Wkp, Wvp, Wf, Wb,
                                   s16, WcT, WfT, wbf);
  k_projm<<<dim3(72, 32), 64, 0, stream>>>(s16, WcT, P);
  k_prep<<<96, 64, 0, stream>>>(P, rot, trans, gamma, eqb, ekb, mq, mk, vT, vpT);
  k_aux<<<1064, 768, 0, stream>>>(eqb, ekb, mk, ext, vT, vpT, vfrag);
  k_fused9<<<dim3(512, 2), 512, 0, stream>>>(z_ij, wbf, ext, vfrag, pp);
  k_merge<<<512, 256, 0, stream>>>(pp, rot, trans, f16);
  k_outm2<<<dim3(24, 16), 256, 0, stream>>>(f16, WfT, bf, out);
}